// Round 9
// baseline (550.966 us; speedup 1.0000x reference)
//
#include <hip/hip_runtime.h>
#include <math.h>

#define IN_F 128
#define C1 32            // 2 heads * 16
#define NEG 0.2f
#define XPAD 132         // padded x-row in LDS
#define BSZ 128          // nodes per bucket (dst>>7)
#define CAP 2560         // edge slots per bucket (mean ~2175, ~8 sigma)
#define EPB 2048         // edges per multisplit block

typedef _Float16 h16;
typedef _Float16 h16x4 __attribute__((ext_vector_type(4)));

__device__ __forceinline__ float leaky(float x) { return x >= 0.f ? x : NEG * x; }

// ------- fat kernel: proj1 (blocks 0..nproj-1) | mscat (rest) -----------
// proj: R7-proven form — 32 nodes/block, xs staged in LDS, W in LDS.
// mscat: LDS-histogram multisplit of edges into 782 dst-buckets.
__global__ __launch_bounds__(256)
void k_fat(const float* __restrict__ x, const float* __restrict__ W1,
           const float* __restrict__ a_s, const float* __restrict__ a_d,
           h16* __restrict__ h1h, float* __restrict__ as1,
           float* __restrict__ ad1, int N,
           const int* __restrict__ ei, int E, int ET, int nbk,
           int* __restrict__ bcnt, int* __restrict__ ebuf, int nproj) {
    __shared__ float smem[IN_F * C1 + 32 * XPAD];   // 33.3 KB union
    int t = threadIdx.x;
    if ((int)blockIdx.x < nproj) {
        // ---------------- projection branch (R7) ----------------
        float* Wl = smem;                                  // [k][32]
        float(*xs)[XPAD] = (float(*)[XPAD])(smem + IN_F * C1);
        for (int i = t; i < IN_F * C1 / 4; i += 256)
            ((float4*)Wl)[i] = ((const float4*)W1)[i];
        int nl = t >> 3, colq = t & 7;
        int node = blockIdx.x * 32 + nl;
        if (node < N) {
            const float4* xr = (const float4*)(x + (size_t)node * IN_F);
            #pragma unroll
            for (int q = 0; q < 4; ++q) {
                int f4 = colq + q * 8;
                *(float4*)&xs[nl][f4 * 4] = xr[f4];
            }
        }
        __syncthreads();
        if (node >= N) return;
        float4 acc = {0.f, 0.f, 0.f, 0.f};
        const float4* wp = (const float4*)Wl;      // [k][8] float4
        #pragma unroll 4
        for (int k4 = 0; k4 < IN_F / 4; ++k4) {
            float4 xv = *(const float4*)&xs[nl][k4 * 4];
            float4 w0 = wp[(k4 * 4 + 0) * 8 + colq];
            float4 w1 = wp[(k4 * 4 + 1) * 8 + colq];
            float4 w2 = wp[(k4 * 4 + 2) * 8 + colq];
            float4 w3 = wp[(k4 * 4 + 3) * 8 + colq];
            acc.x = fmaf(xv.x, w0.x, acc.x); acc.y = fmaf(xv.x, w0.y, acc.y);
            acc.z = fmaf(xv.x, w0.z, acc.z); acc.w = fmaf(xv.x, w0.w, acc.w);
            acc.x = fmaf(xv.y, w1.x, acc.x); acc.y = fmaf(xv.y, w1.y, acc.y);
            acc.z = fmaf(xv.y, w1.z, acc.z); acc.w = fmaf(xv.y, w1.w, acc.w);
            acc.x = fmaf(xv.z, w2.x, acc.x); acc.y = fmaf(xv.z, w2.y, acc.y);
            acc.z = fmaf(xv.z, w2.z, acc.z); acc.w = fmaf(xv.z, w2.w, acc.w);
            acc.x = fmaf(xv.w, w3.x, acc.x); acc.y = fmaf(xv.w, w3.y, acc.y);
            acc.z = fmaf(xv.w, w3.z, acc.z); acc.w = fmaf(xv.w, w3.w, acc.w);
        }
        h16x4 hv = { (h16)acc.x, (h16)acc.y, (h16)acc.z, (h16)acc.w };
        *(h16x4*)(h1h + (size_t)node * C1 + colq * 4) = hv;
        int cb = colq * 4;
        float sv = acc.x * a_s[cb] + acc.y * a_s[cb + 1] + acc.z * a_s[cb + 2] + acc.w * a_s[cb + 3];
        float dv = acc.x * a_d[cb] + acc.y * a_d[cb + 1] + acc.z * a_d[cb + 2] + acc.w * a_d[cb + 3];
        sv += __shfl_xor(sv, 1); dv += __shfl_xor(dv, 1);
        sv += __shfl_xor(sv, 2); dv += __shfl_xor(dv, 2);
        if (colq == 0) { as1[node * 2 + 0] = sv; ad1[node * 2 + 0] = dv; }
        if (colq == 4) { as1[node * 2 + 1] = sv; ad1[node * 2 + 1] = dv; }
    } else {
        // ---------------- multisplit branch ----------------
        int* hist = (int*)smem;                 // 1024
        int* lcur = hist + 1024;                // 1024
        int2* ecache = (int2*)(lcur + 1024);    // EPB int2 = 16 KB
        int bid = blockIdx.x - nproj;
        hist[t] = 0; hist[t + 256] = 0; hist[t + 512] = 0; hist[t + 768] = 0;
        __syncthreads();
        int i0 = bid * EPB, i1 = min(ET, i0 + EPB);
        for (int i = i0 + t; i < i1; i += 256) {
            int s, d;
            if (i < E) { s = ei[i]; d = ei[E + i]; } else { s = d = i - E; }
            ecache[i - i0] = make_int2(s, d);
            atomicAdd(&hist[d >> 7], 1);
        }
        __syncthreads();
        for (int b = t; b < nbk; b += 256) {
            int h = hist[b];
            int base = h ? atomicAdd(&bcnt[b], h) : 0;
            lcur[b] = b * CAP + base;
        }
        __syncthreads();
        for (int i = i0 + t; i < i1; i += 256) {
            int2 e = ecache[i - i0];
            int bkt = e.y >> 7;
            int pos = atomicAdd(&lcur[bkt], 1);
            if (pos < (bkt + 1) * CAP)             // safety net vs overflow
                ebuf[pos] = (e.x << 7) | (e.y & 127);
        }
    }
}

// ---- layer-1 aggregation: per-bucket LDS accumulate + epilogue ---------
// 64 edge-slots x 8 ch-lanes; weights in fp32; acc stride 33 (bank=(dl+c)%32).
__global__ __launch_bounds__(512)
void k_agg1(const int* __restrict__ bcnt, const int* __restrict__ ebuf,
            int N, const float* __restrict__ as1, const float* __restrict__ ad1,
            const float* __restrict__ b1, const float* __restrict__ W2,
            const h16* __restrict__ h1h, float* __restrict__ p2) {
    __shared__ float acc[BSZ][33];       // 16.9 KB
    __shared__ float den[BSZ * 3];       // stride 3 (coprime 32)
    __shared__ float adl[BSZ * 2];
    int b = blockIdx.x, t = threadIdx.x;
    int cnt = min(bcnt[b], CAP);
    int ebase = b * CAP;
    int n0 = b << 7;
    for (int i = t; i < BSZ * 33; i += 512) ((float*)acc)[i] = 0.f;
    for (int i = t; i < BSZ * 3; i += 512) den[i] = 0.f;
    if (t < BSZ) {
        int n = n0 + t;
        float2 v = (n < N) ? ((const float2*)ad1)[n] : make_float2(0.f, 0.f);
        adl[t * 2] = v.x; adl[t * 2 + 1] = v.y;
    }
    __syncthreads();
    int slot = t >> 3, l = t & 7, c0 = l * 4;
    for (int i = slot; i < cnt; i += 64) {
        int e = ebuf[ebase + i];                    // 8-lane broadcast
        int dl = e & 127, s = e >> 7;
        float2 asv = ((const float2*)as1)[s];       // 8B broadcast gather
        float w0 = __expf(leaky(asv.x + adl[dl * 2 + 0]));
        float w1 = __expf(leaky(asv.y + adl[dl * 2 + 1]));
        float wh = (c0 < 16) ? w0 : w1;
        h16x4 hv = *(const h16x4*)(h1h + ((size_t)s << 5) + c0);  // 8B/lane, 64B/edge
        atomicAdd(&acc[dl][c0 + 0], wh * (float)hv.x);
        atomicAdd(&acc[dl][c0 + 1], wh * (float)hv.y);
        atomicAdd(&acc[dl][c0 + 2], wh * (float)hv.z);
        atomicAdd(&acc[dl][c0 + 3], wh * (float)hv.w);
        if (l == 0) atomicAdd(&den[dl * 3 + 0], w0);
        if (l == 4) atomicAdd(&den[dl * 3 + 1], w1);
    }
    __syncthreads();
    // epilogue: normalize + bias + ELU + dot W2 -> p2 (64 slots x 2 passes)
    int head = c0 >> 4;
    float b1l[4] = { b1[c0], b1[c0 + 1], b1[c0 + 2], b1[c0 + 3] };
    float w2l[4] = { W2[c0], W2[c0 + 1], W2[c0 + 2], W2[c0 + 3] };
    #pragma unroll
    for (int p = 0; p < 2; ++p) {
        int dl = slot + p * 64;
        int node = n0 + dl;
        float inv = 1.f / (den[dl * 3 + head] + 1e-16f);
        float val = 0.f, o;
        o = acc[dl][c0 + 0] * inv + b1l[0]; o = o > 0.f ? o : expm1f(o); val = fmaf(o, w2l[0], val);
        o = acc[dl][c0 + 1] * inv + b1l[1]; o = o > 0.f ? o : expm1f(o); val = fmaf(o, w2l[1], val);
        o = acc[dl][c0 + 2] * inv + b1l[2]; o = o > 0.f ? o : expm1f(o); val = fmaf(o, w2l[2], val);
        o = acc[dl][c0 + 3] * inv + b1l[3]; o = o > 0.f ? o : expm1f(o); val = fmaf(o, w2l[3], val);
        val += __shfl_xor(val, 1); val += __shfl_xor(val, 2); val += __shfl_xor(val, 4);
        if (l == 0 && node < N) p2[node] = val;
    }
}

// ---- layer-2: per-bucket scalar edge-parallel LDS accumulate -----------
__global__ __launch_bounds__(512)
void k_agg2(const int* __restrict__ bcnt, const int* __restrict__ ebuf,
            int N, const float* __restrict__ p2, const float* __restrict__ as2,
            const float* __restrict__ ad2, const float* __restrict__ b2,
            float* __restrict__ out) {
    __shared__ float nd[BSZ * 3];        // den, num interleaved (stride 3)
    __shared__ float p2l[BSZ];
    int b = blockIdx.x, t = threadIdx.x;
    int cnt = min(bcnt[b], CAP);
    int ebase = b * CAP;
    int n0 = b << 7;
    for (int i = t; i < BSZ * 3; i += 512) nd[i] = 0.f;
    if (t < BSZ) { int n = n0 + t; p2l[t] = (n < N) ? p2[n] : 0.f; }
    __syncthreads();
    float A = as2[0], Ad = ad2[0];
    for (int i = t; i < cnt; i += 512) {
        int e = ebuf[ebase + i];                   // coalesced
        int dl = e & 127, s = e >> 7;
        float ps = p2[s];                          // L2-resident 4B gather
        float w = __expf(leaky(fmaf(ps, A, Ad * p2l[dl])));
        atomicAdd(&nd[dl * 3 + 0], w);
        atomicAdd(&nd[dl * 3 + 1], w * ps);
    }
    __syncthreads();
    if (t < BSZ && n0 + t < N)
        out[n0 + t] = nd[t * 3 + 1] / (nd[t * 3 + 0] + 1e-16f) + b2[0];
}

extern "C" void kernel_launch(void* const* d_in, const int* in_sizes, int n_in,
                              void* d_out, int out_size, void* d_ws, size_t ws_size,
                              hipStream_t stream) {
    const float* x    = (const float*)d_in[0];
    const int*   ei   = (const int*)d_in[1];
    const float* W1   = (const float*)d_in[2];
    const float* a_s1 = (const float*)d_in[3];
    const float* a_d1 = (const float*)d_in[4];
    const float* b1   = (const float*)d_in[5];
    const float* W2   = (const float*)d_in[6];
    const float* a_s2 = (const float*)d_in[7];
    const float* a_d2 = (const float*)d_in[8];
    const float* b2   = (const float*)d_in[9];
    float* out = (float*)d_out;

    const int N  = in_sizes[0] / IN_F;   // 100000
    const int E  = in_sizes[1] / 2;      // 1600000
    const int ET = E + N;
    const int nbk = (N + BSZ - 1) / BSZ;              // 782 buckets

    // workspace (~16.5 MB; only bcnt needs zeroing)
    float* w   = (float*)d_ws;
    float* as1 = w; w += (size_t)2 * N;
    float* ad1 = w; w += (size_t)2 * N;
    float* p2  = w; w += (size_t)N;
    h16* h1h   = (h16*)w;                // 32*N halves
    w += (size_t)16 * N;
    int* iw     = (int*)w;
    int* bcnt   = iw; iw += 1024;
    int* ebuf   = iw; iw += (size_t)nbk * CAP;

    const int B = 256;
    const int nproj = (N + 31) / 32;                  // 3125 proj blocks
    const int nblkA = (ET + EPB - 1) / EPB;           // 831 multisplit blocks

    hipMemsetAsync(bcnt, 0, 1024 * sizeof(int), stream);
    k_fat <<<nproj + nblkA, B, 0, stream>>>(x, W1, a_s1, a_d1, h1h, as1, ad1, N,
                                            ei, E, ET, nbk, bcnt, ebuf, nproj);
    k_agg1<<<nbk, 512, 0, stream>>>(bcnt, ebuf, N, as1, ad1, b1, W2, h1h, p2);
    k_agg2<<<nbk, 512, 0, stream>>>(bcnt, ebuf, N, p2, a_s2, a_d2, b2, out);
}

// Round 10
// 199.852 us; speedup vs baseline: 2.7569x; 2.7569x over previous
//
#include <hip/hip_runtime.h>
#include <math.h>

#define IN_F 128
#define C1 32            // 2 heads * 16
#define NEG 0.2f
#define BSZ 256          // nodes per fine bucket (dst>>8)
#define CAP 4992         // edge-slot capacity per bucket (mean 4352, ~10 sigma)
#define EPB 2048         // edges per multisplit block
#define TPW 2            // 16-node tiles per wave in proj branch

typedef _Float16 h16;
typedef _Float16 h16x2 __attribute__((ext_vector_type(2)));
typedef _Float16 h16x4 __attribute__((ext_vector_type(4)));
typedef _Float16 h16x8 __attribute__((ext_vector_type(8)));
typedef float f32x4 __attribute__((ext_vector_type(4)));

__device__ __forceinline__ float leaky(float x) { return x >= 0.f ? x : NEG * x; }

// ------- fat kernel: proj1 (blocks 0..nproj-1) | mscat (rest) -----------
// proj: MFMA 16x16x32_f16. Per wave: W held in 8 reg B-fragments (loaded
//       once, L2-hot); per 16-node tile: 8 coalesced float4 x-loads/lane
//       (full line utilization), 8 MFMA, epilogue h1h/as1/ad1.
//       Layouts (HW-verified m89/m120): A[m=lane&15][k=quad*8+j],
//       B[k=quad*8+j][n=lane&15], D[row=quad*4+reg][col=lane&15].
// mscat: LDS-histogram multisplit of edges into 391 dst-buckets (R7).
__global__ __launch_bounds__(256)
void k_fat(const float* __restrict__ x, const float* __restrict__ W1,
           const float* __restrict__ a_s, const float* __restrict__ a_d,
           h16* __restrict__ h1h, float* __restrict__ as1,
           float* __restrict__ ad1, int N,
           const int* __restrict__ ei, int E, int ET, int nbk,
           int* __restrict__ bcnt, int* __restrict__ ebuf, int nproj) {
    __shared__ int smem[5120];                   // 20 KB (mscat branch only)
    int t = threadIdx.x;
    if ((int)blockIdx.x < nproj) {
        // ---------------- MFMA projection branch ----------------
        int wid = t >> 6, lane = t & 63;
        int q = lane >> 4, r = lane & 15;
        // B fragments: W1[k][n], k = kc*32 + q*8 + j, n = ct*16 + r
        h16x8 Bf[2][4];
        #pragma unroll
        for (int ct = 0; ct < 2; ++ct)
            #pragma unroll
            for (int kc = 0; kc < 4; ++kc)
                #pragma unroll
                for (int j = 0; j < 8; ++j)
                    Bf[ct][kc][j] = (h16)W1[(kc * 32 + q * 8 + j) * C1 + ct * 16 + r];
        float a_s0 = a_s[r], a_s1v = a_s[16 + r];
        float a_d0 = a_d[r], a_d1v = a_d[16 + r];
        #pragma unroll
        for (int tt = 0; tt < TPW; ++tt) {
            int tile = (blockIdx.x * 4 + wid) * TPW + tt;
            int m0 = tile << 4;
            if (m0 >= N) break;
            int row = m0 + r; if (row >= N) row = N - 1;
            const float* xr = x + (size_t)row * IN_F + q * 8;
            f32x4 acc0 = {0.f, 0.f, 0.f, 0.f};
            f32x4 acc1 = {0.f, 0.f, 0.f, 0.f};
            #pragma unroll
            for (int kc = 0; kc < 4; ++kc) {
                float4 xa = *(const float4*)(xr + kc * 32);
                float4 xb = *(const float4*)(xr + kc * 32 + 4);
                h16x8 A;
                A[0] = (h16)xa.x; A[1] = (h16)xa.y; A[2] = (h16)xa.z; A[3] = (h16)xa.w;
                A[4] = (h16)xb.x; A[5] = (h16)xb.y; A[6] = (h16)xb.z; A[7] = (h16)xb.w;
                acc0 = __builtin_amdgcn_mfma_f32_16x16x32_f16(A, Bf[0][kc], acc0, 0, 0, 0);
                acc1 = __builtin_amdgcn_mfma_f32_16x16x32_f16(A, Bf[1][kc], acc1, 0, 0, 0);
            }
            #pragma unroll
            for (int reg = 0; reg < 4; ++reg) {
                int node = m0 + q * 4 + reg;
                bool vld = node < N;
                float h0 = acc0[reg], h1 = acc1[reg];
                if (vld) {
                    h1h[(size_t)node * C1 + r]      = (h16)h0;
                    h1h[(size_t)node * C1 + 16 + r] = (h16)h1;
                }
                float s0 = h0 * a_s0, s1 = h1 * a_s1v;
                float d0 = h0 * a_d0, d1 = h1 * a_d1v;
                s0 += __shfl_xor(s0, 1); s0 += __shfl_xor(s0, 2); s0 += __shfl_xor(s0, 4); s0 += __shfl_xor(s0, 8);
                s1 += __shfl_xor(s1, 1); s1 += __shfl_xor(s1, 2); s1 += __shfl_xor(s1, 4); s1 += __shfl_xor(s1, 8);
                d0 += __shfl_xor(d0, 1); d0 += __shfl_xor(d0, 2); d0 += __shfl_xor(d0, 4); d0 += __shfl_xor(d0, 8);
                d1 += __shfl_xor(d1, 1); d1 += __shfl_xor(d1, 2); d1 += __shfl_xor(d1, 4); d1 += __shfl_xor(d1, 8);
                if (vld && r == 0) {
                    *(float2*)&as1[node * 2] = make_float2(s0, s1);
                    *(float2*)&ad1[node * 2] = make_float2(d0, d1);
                }
            }
        }
    } else {
        // ---------------- multisplit branch (R7) ----------------
        int* hist = smem;                       // 512
        int* lcur = hist + 512;                 // 512
        int2* ecache = (int2*)(lcur + 512);     // EPB int2 = 16 KB
        int bid = blockIdx.x - nproj;
        hist[t] = 0; hist[t + 256] = 0;
        __syncthreads();
        int i0 = bid * EPB, i1 = min(ET, i0 + EPB);
        for (int i = i0 + t; i < i1; i += 256) {
            int s, d;
            if (i < E) { s = ei[i]; d = ei[E + i]; } else { s = d = i - E; }
            ecache[i - i0] = make_int2(s, d);
            atomicAdd(&hist[d >> 8], 1);
        }
        __syncthreads();
        for (int b = t; b < nbk; b += 256) {
            int h = hist[b];
            int base = h ? atomicAdd(&bcnt[b], h) : 0;
            lcur[b] = b * CAP + base;
        }
        __syncthreads();
        for (int i = i0 + t; i < i1; i += 256) {
            int2 e = ecache[i - i0];
            int bkt = e.y >> 8;
            int pos = atomicAdd(&lcur[bkt], 1);
            if (pos < (bkt + 1) * CAP)             // safety net vs overflow
                ebuf[pos] = (e.x << 8) | (e.y & 255);
        }
    }
}

// -------- per-bucket CSR build + fused attention weights (R7) -----------
__global__ __launch_bounds__(256)
void k_bcsr(const int* __restrict__ bcnt, const int* __restrict__ ebuf,
            int N, int nbk, int ET,
            const float* __restrict__ as1, const float* __restrict__ ad1,
            int* __restrict__ off, int2* __restrict__ csr2) {
    __shared__ int deg[256];
    __shared__ int cur[256];
    __shared__ float adl[512];           // ad1 window for this bucket
    __shared__ int red[4];
    int b = blockIdx.x, t = threadIdx.x;
    // fbase = sum_{k<b} min(bcnt[k], CAP)
    int part = 0;
    for (int k = t; k < b; k += 256) part += min(bcnt[k], CAP);
    part += __shfl_xor(part, 1);  part += __shfl_xor(part, 2);
    part += __shfl_xor(part, 4);  part += __shfl_xor(part, 8);
    part += __shfl_xor(part, 16); part += __shfl_xor(part, 32);
    if ((t & 63) == 0) red[t >> 6] = part;
    int cnt = min(bcnt[b], CAP);
    int ebase = b * CAP;
    int n0 = b * BSZ;
    deg[t] = 0;
    if (n0 + t < N) ((float2*)adl)[t] = ((const float2*)ad1)[n0 + t];
    __syncthreads();
    int fbase = red[0] + red[1] + red[2] + red[3];
    if (b == nbk - 1 && t == 0) off[N] = fbase + cnt;
    for (int i = t; i < cnt; i += 256)
        atomicAdd(&deg[ebuf[ebase + i] & 255], 1);
    __syncthreads();
    int v = deg[t];
    __syncthreads();
    for (int o = 1; o < 256; o <<= 1) {
        int xv = (t >= o) ? deg[t - o] : 0; __syncthreads();
        deg[t] += xv; __syncthreads();
    }
    int excl = deg[t] - v;
    if (n0 + t < N) off[n0 + t] = fbase + excl;
    cur[t] = fbase + excl;
    __syncthreads();
    for (int i = t; i < cnt; i += 256) {
        int e = ebuf[ebase + i];
        int dl = e & 255;
        int s = e >> 8;
        float2 asv = ((const float2*)as1)[s];      // L2-resident 8B gather
        float w0 = __expf(leaky(asv.x + adl[dl * 2 + 0]));
        float w1 = __expf(leaky(asv.y + adl[dl * 2 + 1]));
        h16x2 wp = { (h16)w0, (h16)w1 };
        int p = atomicAdd(&cur[dl], 1);
        int2 rec; rec.x = s; rec.y = *(int*)&wp;
        csr2[p] = rec;
    }
}

// ---- layer-1: gather aggregation with precomputed weights (R7) ---------
__global__ __launch_bounds__(256)
void k_l1agg(const int* __restrict__ off, const int2* __restrict__ csr2,
             const h16* __restrict__ h1h, const float* __restrict__ b1,
             const float* __restrict__ W2, float* __restrict__ p2, int N) {
    int t = threadIdx.x;
    int node = blockIdx.x * 32 + (t >> 3);
    if (node >= N) return;
    int l = t & 7;
    int c0 = l * 4;                 // channels c0..c0+3 (head = l>>2)
    int head = l >> 2;
    float den = 0.f, a0 = 0.f, a1 = 0.f, a2 = 0.f, a3 = 0.f;
    int j0 = off[node], j1 = off[node + 1];   // j1 > j0 (self-loop guaranteed)
    for (int j = j0; j < j1; j += 4) {
        #pragma unroll
        for (int k = 0; k < 4; ++k) {
            int jj = j + k;
            bool valid = jj < j1;
            jj = valid ? jj : j0;             // safe clamp
            int2 e = csr2[jj];                // 8B broadcast
            int s = e.x;
            h16x2 wv = *(h16x2*)&e.y;
            float w = valid ? (float)(head ? wv.y : wv.x) : 0.f;
            h16x4 hv = *(const h16x4*)(h1h + ((size_t)s << 5) + c0);  // 8B gather
            den += w;
            a0 = fmaf(w, (float)hv.x, a0);
            a1 = fmaf(w, (float)hv.y, a1);
            a2 = fmaf(w, (float)hv.z, a2);
            a3 = fmaf(w, (float)hv.w, a3);
        }
    }
    float inv = 1.f / (den + 1e-16f);
    float o, val = 0.f;
    o = a0 * inv + b1[c0 + 0]; o = o > 0.f ? o : expm1f(o); val = fmaf(o, W2[c0 + 0], val);
    o = a1 * inv + b1[c0 + 1]; o = o > 0.f ? o : expm1f(o); val = fmaf(o, W2[c0 + 1], val);
    o = a2 * inv + b1[c0 + 2]; o = o > 0.f ? o : expm1f(o); val = fmaf(o, W2[c0 + 2], val);
    o = a3 * inv + b1[c0 + 3]; o = o > 0.f ? o : expm1f(o); val = fmaf(o, W2[c0 + 3], val);
    val += __shfl_xor(val, 1); val += __shfl_xor(val, 2); val += __shfl_xor(val, 4);
    if (l == 0) p2[node] = val;
}

// ---- layer-2: scalar gather softmax, thread per node, 4-edge unroll (R7)
__global__ void k_l2(const int* __restrict__ off, const int2* __restrict__ csr2,
                     const float* __restrict__ p2, const float* __restrict__ as2,
                     const float* __restrict__ ad2, const float* __restrict__ b2,
                     float* __restrict__ out, int N) {
    int i = blockIdx.x * blockDim.x + threadIdx.x;
    if (i >= N) return;
    float A = as2[0];
    float Bc = ad2[0] * p2[i];
    float den = 0.f, num = 0.f;
    int j0 = off[i], j1 = off[i + 1];
    for (int j = j0; j < j1; j += 4) {
        #pragma unroll
        for (int k = 0; k < 4; ++k) {
            int jj = j + k;
            bool valid = jj < j1;
            int s = csr2[valid ? jj : j0].x;
            float ps = p2[s];                  // 400KB working set: L2-hit
            float w = valid ? __expf(leaky(fmaf(ps, A, Bc))) : 0.f;
            den += w;
            num = fmaf(w, ps, num);
        }
    }
    out[i] = num / (den + 1e-16f) + b2[0];
}

extern "C" void kernel_launch(void* const* d_in, const int* in_sizes, int n_in,
                              void* d_out, int out_size, void* d_ws, size_t ws_size,
                              hipStream_t stream) {
    const float* x    = (const float*)d_in[0];
    const int*   ei   = (const int*)d_in[1];
    const float* W1   = (const float*)d_in[2];
    const float* a_s1 = (const float*)d_in[3];
    const float* a_d1 = (const float*)d_in[4];
    const float* b1   = (const float*)d_in[5];
    const float* W2   = (const float*)d_in[6];
    const float* a_s2 = (const float*)d_in[7];
    const float* a_d2 = (const float*)d_in[8];
    const float* b2   = (const float*)d_in[9];
    float* out = (float*)d_out;

    const int N  = in_sizes[0] / IN_F;   // 100000
    const int E  = in_sizes[1] / 2;      // 1600000
    const int ET = E + N;
    const int nbk = (N + BSZ - 1) / BSZ;              // 391 buckets

    // workspace layout (~30 MB; only bcnt needs zeroing)
    float* w   = (float*)d_ws;
    float* as1 = w; w += (size_t)2 * N;
    float* ad1 = w; w += (size_t)2 * N;
    float* p2  = w; w += (size_t)N;
    h16* h1h   = (h16*)w;                // 32*N halves
    w += (size_t)16 * N;
    int* iw     = (int*)w;
    int* bcnt   = iw; iw += 512;
    int* off    = iw; iw += (N + 1);
    iw += (iw - (int*)d_ws) & 1;         // 8B-align csr2
    int2* csr2  = (int2*)iw; iw += (size_t)2 * ET;
    int* ebuf   = iw; iw += (size_t)nbk * CAP;

    const int B = 256;
    const int ntile = (N + 15) / 16;                  // 6250 16-node tiles
    const int nproj = (ntile + 4 * TPW - 1) / (4 * TPW);  // 782 proj blocks
    const int nblkA = (ET + EPB - 1) / EPB;           // 831 multisplit blocks

    hipMemsetAsync(bcnt, 0, 512 * sizeof(int), stream);
    k_fat  <<<nproj + nblkA, B, 0, stream>>>(x, W1, a_s1, a_d1, h1h, as1, ad1, N,
                                             ei, E, ET, nbk, bcnt, ebuf, nproj);
    k_bcsr <<<nbk, B, 0, stream>>>(bcnt, ebuf, N, nbk, ET, as1, ad1, off, csr2);
    k_l1agg<<<(N + 31) / 32, B, 0, stream>>>(off, csr2, h1h, b1, W2, p2, N);
    k_l2   <<<(N + B - 1) / B, B, 0, stream>>>(off, csr2, p2, a_s2, a_d2, b2, out, N);
}

// Round 11
// 182.749 us; speedup vs baseline: 3.0149x; 1.0936x over previous
//
#include <hip/hip_runtime.h>
#include <math.h>

#define IN_F 128
#define C1 32            // 2 heads * 16
#define NEG 0.2f
#define BSZ 256          // nodes per fine bucket (dst>>8)
#define CAP 4992         // edge-slot capacity per bucket (mean 4352, ~10 sigma)
#define EPB 2048         // edges per multisplit block
#define TPW 2            // 16-node tiles per wave in proj branch

typedef _Float16 h16;
typedef _Float16 h16x2 __attribute__((ext_vector_type(2)));
typedef _Float16 h16x4 __attribute__((ext_vector_type(4)));
typedef _Float16 h16x8 __attribute__((ext_vector_type(8)));
typedef float f32x4 __attribute__((ext_vector_type(4)));

__device__ __forceinline__ float leaky(float x) { return x >= 0.f ? x : NEG * x; }

// ------- fat kernel: proj1 (blocks 0..nproj-1) | mscat (rest) -----------
// proj: MFMA 16x16x32_f16 (R10-proven). mscat: LDS-histogram multisplit.
__global__ __launch_bounds__(256)
void k_fat(const float* __restrict__ x, const float* __restrict__ W1,
           const float* __restrict__ a_s, const float* __restrict__ a_d,
           h16* __restrict__ h1h, float* __restrict__ as1,
           float* __restrict__ ad1, int N,
           const int* __restrict__ ei, int E, int ET, int nbk,
           int* __restrict__ bcnt, int* __restrict__ ebuf, int nproj) {
    __shared__ int smem[5120];                   // 20 KB (mscat branch only)
    int t = threadIdx.x;
    if ((int)blockIdx.x < nproj) {
        // ---------------- MFMA projection branch ----------------
        int wid = t >> 6, lane = t & 63;
        int q = lane >> 4, r = lane & 15;
        h16x8 Bf[2][4];
        #pragma unroll
        for (int ct = 0; ct < 2; ++ct)
            #pragma unroll
            for (int kc = 0; kc < 4; ++kc)
                #pragma unroll
                for (int j = 0; j < 8; ++j)
                    Bf[ct][kc][j] = (h16)W1[(kc * 32 + q * 8 + j) * C1 + ct * 16 + r];
        float a_s0 = a_s[r], a_s1v = a_s[16 + r];
        float a_d0 = a_d[r], a_d1v = a_d[16 + r];
        #pragma unroll
        for (int tt = 0; tt < TPW; ++tt) {
            int tile = (blockIdx.x * 4 + wid) * TPW + tt;
            int m0 = tile << 4;
            if (m0 >= N) break;
            int row = m0 + r; if (row >= N) row = N - 1;
            const float* xr = x + (size_t)row * IN_F + q * 8;
            f32x4 acc0 = {0.f, 0.f, 0.f, 0.f};
            f32x4 acc1 = {0.f, 0.f, 0.f, 0.f};
            #pragma unroll
            for (int kc = 0; kc < 4; ++kc) {
                float4 xa = *(const float4*)(xr + kc * 32);
                float4 xb = *(const float4*)(xr + kc * 32 + 4);
                h16x8 A;
                A[0] = (h16)xa.x; A[1] = (h16)xa.y; A[2] = (h16)xa.z; A[3] = (h16)xa.w;
                A[4] = (h16)xb.x; A[5] = (h16)xb.y; A[6] = (h16)xb.z; A[7] = (h16)xb.w;
                acc0 = __builtin_amdgcn_mfma_f32_16x16x32_f16(A, Bf[0][kc], acc0, 0, 0, 0);
                acc1 = __builtin_amdgcn_mfma_f32_16x16x32_f16(A, Bf[1][kc], acc1, 0, 0, 0);
            }
            #pragma unroll
            for (int reg = 0; reg < 4; ++reg) {
                int node = m0 + q * 4 + reg;
                bool vld = node < N;
                float h0 = acc0[reg], h1 = acc1[reg];
                if (vld) {
                    h1h[(size_t)node * C1 + r]      = (h16)h0;
                    h1h[(size_t)node * C1 + 16 + r] = (h16)h1;
                }
                float s0 = h0 * a_s0, s1 = h1 * a_s1v;
                float d0 = h0 * a_d0, d1 = h1 * a_d1v;
                s0 += __shfl_xor(s0, 1); s0 += __shfl_xor(s0, 2); s0 += __shfl_xor(s0, 4); s0 += __shfl_xor(s0, 8);
                s1 += __shfl_xor(s1, 1); s1 += __shfl_xor(s1, 2); s1 += __shfl_xor(s1, 4); s1 += __shfl_xor(s1, 8);
                d0 += __shfl_xor(d0, 1); d0 += __shfl_xor(d0, 2); d0 += __shfl_xor(d0, 4); d0 += __shfl_xor(d0, 8);
                d1 += __shfl_xor(d1, 1); d1 += __shfl_xor(d1, 2); d1 += __shfl_xor(d1, 4); d1 += __shfl_xor(d1, 8);
                if (vld && r == 0) {
                    *(float2*)&as1[node * 2] = make_float2(s0, s1);
                    *(float2*)&ad1[node * 2] = make_float2(d0, d1);
                }
            }
        }
    } else {
        // ---------------- multisplit branch ----------------
        int* hist = smem;                       // 512
        int* lcur = hist + 512;                 // 512
        int2* ecache = (int2*)(lcur + 512);     // EPB int2 = 16 KB
        int bid = blockIdx.x - nproj;
        hist[t] = 0; hist[t + 256] = 0;
        __syncthreads();
        int i0 = bid * EPB, i1 = min(ET, i0 + EPB);
        for (int i = i0 + t; i < i1; i += 256) {
            int s, d;
            if (i < E) { s = ei[i]; d = ei[E + i]; } else { s = d = i - E; }
            ecache[i - i0] = make_int2(s, d);
            atomicAdd(&hist[d >> 8], 1);
        }
        __syncthreads();
        for (int b = t; b < nbk; b += 256) {
            int h = hist[b];
            int base = h ? atomicAdd(&bcnt[b], h) : 0;
            lcur[b] = b * CAP + base;
        }
        __syncthreads();
        for (int i = i0 + t; i < i1; i += 256) {
            int2 e = ecache[i - i0];
            int bkt = e.y >> 8;
            int pos = atomicAdd(&lcur[bkt], 1);
            if (pos < (bkt + 1) * CAP)             // safety net vs overflow
                ebuf[pos] = (e.x << 8) | (e.y & 255);
        }
    }
}

// ---- fused bucket CSR + layer-1 aggregation + epilogue -----------------
// Per bucket (512 thr): LDS histogram/scan of 256 nodes, weighted edge
// records placed into a SORTED LDS list (int atomics only), slim src-only
// csr1 to global for layer-2, then node-parallel aggregation (8 lanes/node,
// edge records read from LDS; only h1h line-gathers go to global) + ELU/W2.
__global__ __launch_bounds__(512)
void k_bagg(const int* __restrict__ bcnt, const int* __restrict__ ebuf,
            int N, int nbk, int ET,
            const float* __restrict__ as1, const float* __restrict__ ad1,
            const float* __restrict__ b1, const float* __restrict__ W2,
            const h16* __restrict__ h1h, int* __restrict__ off,
            int* __restrict__ csr1, float* __restrict__ p2) {
    __shared__ int2 elist[CAP];          // 39.9 KB sorted (src, fp16 w0|w1)
    __shared__ int deg[256], sst[256], cur[256];
    __shared__ float adl[512];
    __shared__ int red[8];
    int b = blockIdx.x, t = threadIdx.x;
    int cnt = min(bcnt[b], CAP);
    int ebase = b * CAP;
    int n0 = b * BSZ;
    // fbase = sum_{k<b} min(bcnt[k],CAP)
    int part = 0;
    for (int k = t; k < b; k += 512) part += min(bcnt[k], CAP);
    part += __shfl_xor(part, 1);  part += __shfl_xor(part, 2);
    part += __shfl_xor(part, 4);  part += __shfl_xor(part, 8);
    part += __shfl_xor(part, 16); part += __shfl_xor(part, 32);
    if ((t & 63) == 0) red[t >> 6] = part;
    if (t < 256) {
        deg[t] = 0;
        int n = n0 + t;
        float2 v = (n < N) ? ((const float2*)ad1)[n] : make_float2(0.f, 0.f);
        adl[t * 2] = v.x; adl[t * 2 + 1] = v.y;
    }
    __syncthreads();
    int fbase = red[0] + red[1] + red[2] + red[3] + red[4] + red[5] + red[6] + red[7];
    if (b == nbk - 1 && t == 0) off[N] = ET;
    // histogram
    for (int i = t; i < cnt; i += 512)
        atomicAdd(&deg[ebuf[ebase + i] & 255], 1);
    __syncthreads();
    int v = (t < 256) ? deg[t] : 0;
    __syncthreads();
    for (int o = 1; o < 256; o <<= 1) {
        int xv = (t >= o && t < 256) ? deg[t - o] : 0;
        __syncthreads();
        if (t < 256) deg[t] += xv;                 // deg -> inclusive scan
        __syncthreads();
    }
    if (t < 256) {
        int excl = deg[t] - v;
        sst[t] = excl; cur[t] = excl;
        if (n0 + t < N) off[n0 + t] = fbase + excl;
    }
    __syncthreads();
    // weighted placement into sorted LDS list + slim global csr1
    for (int i = t; i < cnt; i += 512) {
        int e = ebuf[ebase + i];
        int dl = e & 255, s = e >> 8;
        float2 asv = ((const float2*)as1)[s];      // L2-resident 8B gather
        float w0 = __expf(leaky(asv.x + adl[dl * 2 + 0]));
        float w1 = __expf(leaky(asv.y + adl[dl * 2 + 1]));
        h16x2 wp = { (h16)w0, (h16)w1 };
        int p = atomicAdd(&cur[dl], 1);
        int2 rec; rec.x = s; rec.y = *(int*)&wp;
        elist[p] = rec;
        csr1[fbase + p] = s;
    }
    __syncthreads();
    // node-parallel aggregation: 64 nodes/pass x 4 passes, 8 lanes/node
    int l = t & 7, slot = t >> 3, c0 = l * 4, head = l >> 2;
    float b1l[4] = { b1[c0], b1[c0 + 1], b1[c0 + 2], b1[c0 + 3] };
    float w2l[4] = { W2[c0], W2[c0 + 1], W2[c0 + 2], W2[c0 + 3] };
    #pragma unroll
    for (int pass = 0; pass < 4; ++pass) {
        int dl = pass * 64 + slot;
        int node = n0 + dl;
        if (node >= N) break;
        int j0 = sst[dl], j1 = deg[dl];            // [start, inclusive-end)
        float den = 0.f, a0 = 0.f, a1 = 0.f, a2 = 0.f, a3 = 0.f;
        for (int j = j0; j < j1; j += 4) {
            #pragma unroll
            for (int k = 0; k < 4; ++k) {
                int jj = j + k;
                bool valid = jj < j1;
                jj = valid ? jj : j0;
                int2 e = elist[jj];                // LDS broadcast
                int s = e.x;
                h16x2 wv = *(h16x2*)&e.y;
                float w = valid ? (float)(head ? wv.y : wv.x) : 0.f;
                h16x4 hv = *(const h16x4*)(h1h + ((size_t)s << 5) + c0);
                den += w;
                a0 = fmaf(w, (float)hv.x, a0);
                a1 = fmaf(w, (float)hv.y, a1);
                a2 = fmaf(w, (float)hv.z, a2);
                a3 = fmaf(w, (float)hv.w, a3);
            }
        }
        float inv = 1.f / (den + 1e-16f);
        float o, val = 0.f;
        o = a0 * inv + b1l[0]; o = o > 0.f ? o : expm1f(o); val = fmaf(o, w2l[0], val);
        o = a1 * inv + b1l[1]; o = o > 0.f ? o : expm1f(o); val = fmaf(o, w2l[1], val);
        o = a2 * inv + b1l[2]; o = o > 0.f ? o : expm1f(o); val = fmaf(o, w2l[2], val);
        o = a3 * inv + b1l[3]; o = o > 0.f ? o : expm1f(o); val = fmaf(o, w2l[3], val);
        val += __shfl_xor(val, 1); val += __shfl_xor(val, 2); val += __shfl_xor(val, 4);
        if (l == 0) p2[node] = val;
    }
}

// ---- layer-2: scalar gather softmax, thread per node, 4-edge unroll ----
__global__ void k_l2(const int* __restrict__ off, const int* __restrict__ csr1,
                     const float* __restrict__ p2, const float* __restrict__ as2,
                     const float* __restrict__ ad2, const float* __restrict__ b2,
                     float* __restrict__ out, int N) {
    int i = blockIdx.x * blockDim.x + threadIdx.x;
    if (i >= N) return;
    float A = as2[0];
    float Bc = ad2[0] * p2[i];
    float den = 0.f, num = 0.f;
    int j0 = off[i], j1 = off[i + 1];
    for (int j = j0; j < j1; j += 4) {
        #pragma unroll
        for (int k = 0; k < 4; ++k) {
            int jj = j + k;
            bool valid = jj < j1;
            int s = csr1[valid ? jj : j0];
            float ps = p2[s];                  // 400KB working set: L2-hit
            float w = valid ? __expf(leaky(fmaf(ps, A, Bc))) : 0.f;
            den += w;
            num = fmaf(w, ps, num);
        }
    }
    out[i] = num / (den + 1e-16f) + b2[0];
}

extern "C" void kernel_launch(void* const* d_in, const int* in_sizes, int n_in,
                              void* d_out, int out_size, void* d_ws, size_t ws_size,
                              hipStream_t stream) {
    const float* x    = (const float*)d_in[0];
    const int*   ei   = (const int*)d_in[1];
    const float* W1   = (const float*)d_in[2];
    const float* a_s1 = (const float*)d_in[3];
    const float* a_d1 = (const float*)d_in[4];
    const float* b1   = (const float*)d_in[5];
    const float* W2   = (const float*)d_in[6];
    const float* a_s2 = (const float*)d_in[7];
    const float* a_d2 = (const float*)d_in[8];
    const float* b2   = (const float*)d_in[9];
    float* out = (float*)d_out;

    const int N  = in_sizes[0] / IN_F;   // 100000
    const int E  = in_sizes[1] / 2;      // 1600000
    const int ET = E + N;
    const int nbk = (N + BSZ - 1) / BSZ;              // 391 buckets

    // workspace layout (~24 MB; only bcnt needs zeroing)
    float* w   = (float*)d_ws;
    float* as1 = w; w += (size_t)2 * N;
    float* ad1 = w; w += (size_t)2 * N;
    float* p2  = w; w += (size_t)N;
    h16* h1h   = (h16*)w;                // 32*N halves
    w += (size_t)16 * N;
    int* iw     = (int*)w;
    int* bcnt   = iw; iw += 512;
    int* off    = iw; iw += (N + 1);
    int* csr1   = iw; iw += ET;
    int* ebuf   = iw; iw += (size_t)nbk * CAP;

    const int B = 256;
    const int ntile = (N + 15) / 16;                  // 6250 16-node tiles
    const int nproj = (ntile + 4 * TPW - 1) / (4 * TPW);  // 782 proj blocks
    const int nblkA = (ET + EPB - 1) / EPB;           // 831 multisplit blocks

    hipMemsetAsync(bcnt, 0, 512 * sizeof(int), stream);
    k_fat <<<nproj + nblkA, B, 0, stream>>>(x, W1, a_s1, a_d1, h1h, as1, ad1, N,
                                            ei, E, ET, nbk, bcnt, ebuf, nproj);
    k_bagg<<<nbk, 512, 0, stream>>>(bcnt, ebuf, N, nbk, ET, as1, ad1, b1, W2,
                                    h1h, off, csr1, p2);
    k_l2  <<<(N + B - 1) / B, B, 0, stream>>>(off, csr1, p2, a_s2, a_d2, b2, out, N);
}

// Round 12
// 180.904 us; speedup vs baseline: 3.0456x; 1.0102x over previous
//
#include <hip/hip_runtime.h>
#include <math.h>

#define IN_F 128
#define C1 32            // 2 heads * 16
#define NEG 0.2f
#define BSZ 128          // nodes per fine bucket (dst>>7)
#define CAP 2560         // edge-slot capacity per bucket (mean ~2175, +8 sigma)
#define EPB 2048         // edges per multisplit block
#define TPW 2            // 16-node tiles per wave in proj branch

typedef _Float16 h16;
typedef _Float16 h16x2 __attribute__((ext_vector_type(2)));
typedef _Float16 h16x4 __attribute__((ext_vector_type(4)));
typedef _Float16 h16x8 __attribute__((ext_vector_type(8)));
typedef float f32x4 __attribute__((ext_vector_type(4)));

__device__ __forceinline__ float leaky(float x) { return x >= 0.f ? x : NEG * x; }

// ------- fat kernel: proj1 (blocks 0..nproj-1) | mscat (rest) -----------
// proj: MFMA 16x16x32_f16 (R10-proven). mscat: LDS-histogram multisplit
// into 782 dst-buckets (d>>7).
__global__ __launch_bounds__(256)
void k_fat(const float* __restrict__ x, const float* __restrict__ W1,
           const float* __restrict__ a_s, const float* __restrict__ a_d,
           h16* __restrict__ h1h, float* __restrict__ as1,
           float* __restrict__ ad1, int N,
           const int* __restrict__ ei, int E, int ET, int nbk,
           int* __restrict__ bcnt, int* __restrict__ ebuf, int nproj) {
    __shared__ int smem[6144];                   // 24 KB (mscat branch only)
    int t = threadIdx.x;
    if ((int)blockIdx.x < nproj) {
        // ---------------- MFMA projection branch ----------------
        int wid = t >> 6, lane = t & 63;
        int q = lane >> 4, r = lane & 15;
        h16x8 Bf[2][4];
        #pragma unroll
        for (int ct = 0; ct < 2; ++ct)
            #pragma unroll
            for (int kc = 0; kc < 4; ++kc)
                #pragma unroll
                for (int j = 0; j < 8; ++j)
                    Bf[ct][kc][j] = (h16)W1[(kc * 32 + q * 8 + j) * C1 + ct * 16 + r];
        float a_s0 = a_s[r], a_s1v = a_s[16 + r];
        float a_d0 = a_d[r], a_d1v = a_d[16 + r];
        #pragma unroll
        for (int tt = 0; tt < TPW; ++tt) {
            int tile = (blockIdx.x * 4 + wid) * TPW + tt;
            int m0 = tile << 4;
            if (m0 >= N) break;
            int row = m0 + r; if (row >= N) row = N - 1;
            const float* xr = x + (size_t)row * IN_F + q * 8;
            f32x4 acc0 = {0.f, 0.f, 0.f, 0.f};
            f32x4 acc1 = {0.f, 0.f, 0.f, 0.f};
            #pragma unroll
            for (int kc = 0; kc < 4; ++kc) {
                float4 xa = *(const float4*)(xr + kc * 32);
                float4 xb = *(const float4*)(xr + kc * 32 + 4);
                h16x8 A;
                A[0] = (h16)xa.x; A[1] = (h16)xa.y; A[2] = (h16)xa.z; A[3] = (h16)xa.w;
                A[4] = (h16)xb.x; A[5] = (h16)xb.y; A[6] = (h16)xb.z; A[7] = (h16)xb.w;
                acc0 = __builtin_amdgcn_mfma_f32_16x16x32_f16(A, Bf[0][kc], acc0, 0, 0, 0);
                acc1 = __builtin_amdgcn_mfma_f32_16x16x32_f16(A, Bf[1][kc], acc1, 0, 0, 0);
            }
            #pragma unroll
            for (int reg = 0; reg < 4; ++reg) {
                int node = m0 + q * 4 + reg;
                bool vld = node < N;
                float h0 = acc0[reg], h1 = acc1[reg];
                if (vld) {
                    h1h[(size_t)node * C1 + r]      = (h16)h0;
                    h1h[(size_t)node * C1 + 16 + r] = (h16)h1;
                }
                float s0 = h0 * a_s0, s1 = h1 * a_s1v;
                float d0 = h0 * a_d0, d1 = h1 * a_d1v;
                s0 += __shfl_xor(s0, 1); s0 += __shfl_xor(s0, 2); s0 += __shfl_xor(s0, 4); s0 += __shfl_xor(s0, 8);
                s1 += __shfl_xor(s1, 1); s1 += __shfl_xor(s1, 2); s1 += __shfl_xor(s1, 4); s1 += __shfl_xor(s1, 8);
                d0 += __shfl_xor(d0, 1); d0 += __shfl_xor(d0, 2); d0 += __shfl_xor(d0, 4); d0 += __shfl_xor(d0, 8);
                d1 += __shfl_xor(d1, 1); d1 += __shfl_xor(d1, 2); d1 += __shfl_xor(d1, 4); d1 += __shfl_xor(d1, 8);
                if (vld && r == 0) {
                    *(float2*)&as1[node * 2] = make_float2(s0, s1);
                    *(float2*)&ad1[node * 2] = make_float2(d0, d1);
                }
            }
        }
    } else {
        // ---------------- multisplit branch ----------------
        int* hist = smem;                       // 1024
        int* lcur = hist + 1024;                // 1024
        int2* ecache = (int2*)(lcur + 1024);    // EPB int2 = 16 KB
        int bid = blockIdx.x - nproj;
        hist[t] = 0; hist[t + 256] = 0; hist[t + 512] = 0; hist[t + 768] = 0;
        __syncthreads();
        int i0 = bid * EPB, i1 = min(ET, i0 + EPB);
        for (int i = i0 + t; i < i1; i += 256) {
            int s, d;
            if (i < E) { s = ei[i]; d = ei[E + i]; } else { s = d = i - E; }
            ecache[i - i0] = make_int2(s, d);
            atomicAdd(&hist[d >> 7], 1);
        }
        __syncthreads();
        for (int b = t; b < nbk; b += 256) {
            int h = hist[b];
            int base = h ? atomicAdd(&bcnt[b], h) : 0;
            lcur[b] = b * CAP + base;
        }
        __syncthreads();
        for (int i = i0 + t; i < i1; i += 256) {
            int2 e = ecache[i - i0];
            int bkt = e.y >> 7;
            int pos = atomicAdd(&lcur[bkt], 1);
            if (pos < (bkt + 1) * CAP)             // safety net vs overflow
                ebuf[pos] = (e.x << 7) | (e.y & 127);
        }
    }
}

// ---- fused bucket CSR + layer-1 aggregation + epilogue -----------------
// Per 128-node bucket (512 thr): LDS histogram/scan, weighted edge records
// into sorted LDS list, slim src-only csr1 to global, then node-parallel
// aggregation (8 lanes/node; only h1h line-gathers hit global) + ELU/W2.
__global__ __launch_bounds__(512)
void k_bagg(const int* __restrict__ bcnt, const int* __restrict__ ebuf,
            int N, int nbk, int ET,
            const float* __restrict__ as1, const float* __restrict__ ad1,
            const float* __restrict__ b1, const float* __restrict__ W2,
            const h16* __restrict__ h1h, int* __restrict__ off,
            int* __restrict__ csr1, float* __restrict__ p2) {
    __shared__ int2 elist[CAP];          // 20.5 KB sorted (src, fp16 w0|w1)
    __shared__ int deg[BSZ], sst[BSZ], cur[BSZ];
    __shared__ float adl[BSZ * 2];
    __shared__ int red[8];
    int b = blockIdx.x, t = threadIdx.x;
    int cnt = min(bcnt[b], CAP);
    int ebase = b * CAP;
    int n0 = b * BSZ;
    // fbase = sum_{k<b} min(bcnt[k],CAP)
    int part = 0;
    for (int k = t; k < b; k += 512) part += min(bcnt[k], CAP);
    part += __shfl_xor(part, 1);  part += __shfl_xor(part, 2);
    part += __shfl_xor(part, 4);  part += __shfl_xor(part, 8);
    part += __shfl_xor(part, 16); part += __shfl_xor(part, 32);
    if ((t & 63) == 0) red[t >> 6] = part;
    if (t < BSZ) {
        deg[t] = 0;
        int n = n0 + t;
        float2 v = (n < N) ? ((const float2*)ad1)[n] : make_float2(0.f, 0.f);
        adl[t * 2] = v.x; adl[t * 2 + 1] = v.y;
    }
    __syncthreads();
    int fbase = red[0] + red[1] + red[2] + red[3] + red[4] + red[5] + red[6] + red[7];
    if (b == nbk - 1 && t == 0) off[N] = ET;
    // histogram
    for (int i = t; i < cnt; i += 512)
        atomicAdd(&deg[ebuf[ebase + i] & 127], 1);
    __syncthreads();
    int v = (t < BSZ) ? deg[t] : 0;
    __syncthreads();
    for (int o = 1; o < BSZ; o <<= 1) {
        int xv = (t >= o && t < BSZ) ? deg[t - o] : 0;
        __syncthreads();
        if (t < BSZ) deg[t] += xv;                 // deg -> inclusive scan
        __syncthreads();
    }
    if (t < BSZ) {
        int excl = deg[t] - v;
        sst[t] = excl; cur[t] = excl;
        if (n0 + t < N) off[n0 + t] = fbase + excl;
    }
    __syncthreads();
    // weighted placement into sorted LDS list + slim global csr1
    for (int i = t; i < cnt; i += 512) {
        int e = ebuf[ebase + i];
        int dl = e & 127, s = e >> 7;
        float2 asv = ((const float2*)as1)[s];      // L2-resident 8B gather
        float w0 = __expf(leaky(asv.x + adl[dl * 2 + 0]));
        float w1 = __expf(leaky(asv.y + adl[dl * 2 + 1]));
        h16x2 wp = { (h16)w0, (h16)w1 };
        int p = atomicAdd(&cur[dl], 1);
        int2 rec; rec.x = s; rec.y = *(int*)&wp;
        elist[p] = rec;
        csr1[fbase + p] = s;
    }
    __syncthreads();
    // node-parallel aggregation: 64 nodes/pass x 2 passes, 8 lanes/node
    int l = t & 7, slot = t >> 3, c0 = l * 4, head = l >> 2;
    float b1l[4] = { b1[c0], b1[c0 + 1], b1[c0 + 2], b1[c0 + 3] };
    float w2l[4] = { W2[c0], W2[c0 + 1], W2[c0 + 2], W2[c0 + 3] };
    #pragma unroll
    for (int pass = 0; pass < 2; ++pass) {
        int dl = pass * 64 + slot;
        int node = n0 + dl;
        if (node >= N) break;
        int j0 = sst[dl], j1 = deg[dl];            // [start, inclusive-end)
        float den = 0.f, a0 = 0.f, a1 = 0.f, a2 = 0.f, a3 = 0.f;
        for (int j = j0; j < j1; j += 4) {
            #pragma unroll
            for (int k = 0; k < 4; ++k) {
                int jj = j + k;
                bool valid = jj < j1;
                jj = valid ? jj : j0;
                int2 e = elist[jj];                // LDS broadcast
                int s = e.x;
                h16x2 wv = *(h16x2*)&e.y;
                float w = valid ? (float)(head ? wv.y : wv.x) : 0.f;
                h16x4 hv = *(const h16x4*)(h1h + ((size_t)s << 5) + c0);
                den += w;
                a0 = fmaf(w, (float)hv.x, a0);
                a1 = fmaf(w, (float)hv.y, a1);
                a2 = fmaf(w, (float)hv.z, a2);
                a3 = fmaf(w, (float)hv.w, a3);
            }
        }
        float inv = 1.f / (den + 1e-16f);
        float o, val = 0.f;
        o = a0 * inv + b1l[0]; o = o > 0.f ? o : expm1f(o); val = fmaf(o, w2l[0], val);
        o = a1 * inv + b1l[1]; o = o > 0.f ? o : expm1f(o); val = fmaf(o, w2l[1], val);
        o = a2 * inv + b1l[2]; o = o > 0.f ? o : expm1f(o); val = fmaf(o, w2l[2], val);
        o = a3 * inv + b1l[3]; o = o > 0.f ? o : expm1f(o); val = fmaf(o, w2l[3], val);
        val += __shfl_xor(val, 1); val += __shfl_xor(val, 2); val += __shfl_xor(val, 4);
        if (l == 0) p2[node] = val;
    }
}

// ---- layer-2: scalar gather softmax, thread per node, 4-edge unroll ----
__global__ void k_l2(const int* __restrict__ off, const int* __restrict__ csr1,
                     const float* __restrict__ p2, const float* __restrict__ as2,
                     const float* __restrict__ ad2, const float* __restrict__ b2,
                     float* __restrict__ out, int N) {
    int i = blockIdx.x * blockDim.x + threadIdx.x;
    if (i >= N) return;
    float A = as2[0];
    float Bc = ad2[0] * p2[i];
    float den = 0.f, num = 0.f;
    int j0 = off[i], j1 = off[i + 1];
    for (int j = j0; j < j1; j += 4) {
        #pragma unroll
        for (int k = 0; k < 4; ++k) {
            int jj = j + k;
            bool valid = jj < j1;
            int s = csr1[valid ? jj : j0];
            float ps = p2[s];                  // 400KB working set: L2-hit
            float w = valid ? __expf(leaky(fmaf(ps, A, Bc))) : 0.f;
            den += w;
            num = fmaf(w, ps, num);
        }
    }
    out[i] = num / (den + 1e-16f) + b2[0];
}

extern "C" void kernel_launch(void* const* d_in, const int* in_sizes, int n_in,
                              void* d_out, int out_size, void* d_ws, size_t ws_size,
                              hipStream_t stream) {
    const float* x    = (const float*)d_in[0];
    const int*   ei   = (const int*)d_in[1];
    const float* W1   = (const float*)d_in[2];
    const float* a_s1 = (const float*)d_in[3];
    const float* a_d1 = (const float*)d_in[4];
    const float* b1   = (const float*)d_in[5];
    const float* W2   = (const float*)d_in[6];
    const float* a_s2 = (const float*)d_in[7];
    const float* a_d2 = (const float*)d_in[8];
    const float* b2   = (const float*)d_in[9];
    float* out = (float*)d_out;

    const int N  = in_sizes[0] / IN_F;   // 100000
    const int E  = in_sizes[1] / 2;      // 1600000
    const int ET = E + N;
    const int nbk = (N + BSZ - 1) / BSZ;              // 782 buckets

    // workspace layout (~22 MB; only bcnt needs zeroing)
    float* w   = (float*)d_ws;
    float* as1 = w; w += (size_t)2 * N;
    float* ad1 = w; w += (size_t)2 * N;
    float* p2  = w; w += (size_t)N;
    h16* h1h   = (h16*)w;                // 32*N halves
    w += (size_t)16 * N;
    int* iw     = (int*)w;
    int* bcnt   = iw; iw += 1024;
    int* off    = iw; iw += (N + 1);
    int* csr1   = iw; iw += ET;
    int* ebuf   = iw; iw += (size_t)nbk * CAP;

    const int B = 256;
    const int ntile = (N + 15) / 16;                  // 6250 16-node tiles
    const int nproj = (ntile + 4 * TPW - 1) / (4 * TPW);  // 782 proj blocks
    const int nblkA = (ET + EPB - 1) / EPB;           // 831 multisplit blocks

    hipMemsetAsync(bcnt, 0, 1024 * sizeof(int), stream);
    k_fat <<<nproj + nblkA, B, 0, stream>>>(x, W1, a_s1, a_d1, h1h, as1, ad1, N,
                                            ei, E, ET, nbk, bcnt, ebuf, nproj);
    k_bagg<<<nbk, 512, 0, stream>>>(bcnt, ebuf, N, nbk, ET, as1, ad1, b1, W2,
                                    h1h, off, csr1, p2);
    k_l2  <<<(N + B - 1) / B, B, 0, stream>>>(off, csr1, p2, a_s2, a_d2, b2, out, N);
}